// Round 1
// baseline (7980.139 us; speedup 1.0000x reference)
//
#include <hip/hip_runtime.h>

// GraphSAGE 3-layer eval on MI355X.
// Layer l: agg = segment_sum(in[src], dst, n_dst); h = in[:n_dst]@Wself + agg@Wneigh + b; relu (l<2)
// Sizes (fixed by setup_inputs): N0=400000, N1=100000, N2=25000, N3=6250,
// E0=1.6M, E1=400k, E2=100k, D=H=256, C=47.

#define DIM 256

// ---------------- segment sum: one wave per edge ----------------
__global__ __launch_bounds__(256) void seg_sum_kernel(
    const float* __restrict__ X,      // [n_src, 256]
    const int* __restrict__ src,
    const int* __restrict__ dst,
    float* __restrict__ agg,          // [n_dst, 256], pre-zeroed
    int E)
{
    const int lane  = threadIdx.x & 63;
    const int wave  = (blockIdx.x << 2) + (threadIdx.x >> 6);
    const int nwave = gridDim.x << 2;
    for (int e = wave; e < E; e += nwave) {
        const int s = src[e];
        const int d = dst[e];
        const float4 v = *reinterpret_cast<const float4*>(X + (size_t)s * DIM + lane * 4);
        float* o = agg + (size_t)d * DIM + lane * 4;
        atomicAdd(o + 0, v.x);
        atomicAdd(o + 1, v.y);
        atomicAdd(o + 2, v.z);
        atomicAdd(o + 3, v.w);
    }
}

// ---------------- fused SAGE GEMM: C = A0@B0 + A1@B1 + bias (+relu) ----------------
// A0,A1: [M,256] row-major. B0,B1: [256,N] row-major. C: [M,N].
// 64x64 block tile, BK=16, 256 threads, 4x4 microtile per thread.
template<bool RELU>
__global__ __launch_bounds__(256) void sage_gemm_kernel(
    const float* __restrict__ A0,
    const float* __restrict__ A1,
    const float* __restrict__ B0,
    const float* __restrict__ B1,
    const float* __restrict__ bias,
    float* __restrict__ C,
    int M, int N)
{
    __shared__ float As[16][68];   // [k][m], pad 64->68 keeps write conflicts at free 2-way
    __shared__ float Bs[16][64];   // [k][n]

    const int t  = threadIdx.x;
    const int bm = blockIdx.x * 64;
    const int bn = blockIdx.y * 64;

    // global->LDS load roles
    const int a_row = t >> 2;           // 0..63
    const int a_k4  = (t & 3) << 2;     // 0,4,8,12
    const int b_k   = t >> 4;           // 0..15
    const int b_n4  = (t & 15) << 2;    // 0..60

    // compute roles: 16x16 thread grid, each 4x4 outputs
    const int m0 = (t >> 4) << 2;
    const int n0 = (t & 15) << 2;

    float acc[4][4] = {};

    const int  gm_a      = bm + a_row;
    const bool a_ok      = (gm_a < M);
    const bool n_aligned = ((N & 3) == 0);   // true for N=256 path, false for N=47

    for (int half = 0; half < 2; ++half) {
        const float* __restrict__ A = half ? A1 : A0;
        const float* __restrict__ B = half ? B1 : B0;
        for (int kb = 0; kb < DIM; kb += 16) {
            // stage A tile (row-major global, transposed into LDS)
            float4 av = make_float4(0.f, 0.f, 0.f, 0.f);
            if (a_ok)
                av = *reinterpret_cast<const float4*>(A + (size_t)gm_a * DIM + kb + a_k4);
            // stage B tile
            float4 bv;
            const int gk = kb + b_k;
            const int gn = bn + b_n4;
            if (n_aligned) {
                bv = *reinterpret_cast<const float4*>(B + (size_t)gk * N + gn);
            } else {
                const float* Brow = B + (size_t)gk * N;
                bv.x = (gn + 0 < N) ? Brow[gn + 0] : 0.f;
                bv.y = (gn + 1 < N) ? Brow[gn + 1] : 0.f;
                bv.z = (gn + 2 < N) ? Brow[gn + 2] : 0.f;
                bv.w = (gn + 3 < N) ? Brow[gn + 3] : 0.f;
            }

            __syncthreads();   // previous tile fully consumed
            As[a_k4 + 0][a_row] = av.x;
            As[a_k4 + 1][a_row] = av.y;
            As[a_k4 + 2][a_row] = av.z;
            As[a_k4 + 3][a_row] = av.w;
            *reinterpret_cast<float4*>(&Bs[b_k][b_n4]) = bv;
            __syncthreads();   // tile visible

#pragma unroll
            for (int k = 0; k < 16; ++k) {
                const float4 a = *reinterpret_cast<const float4*>(&As[k][m0]);
                const float4 b = *reinterpret_cast<const float4*>(&Bs[k][n0]);
                acc[0][0] += a.x * b.x; acc[0][1] += a.x * b.y; acc[0][2] += a.x * b.z; acc[0][3] += a.x * b.w;
                acc[1][0] += a.y * b.x; acc[1][1] += a.y * b.y; acc[1][2] += a.y * b.z; acc[1][3] += a.y * b.w;
                acc[2][0] += a.z * b.x; acc[2][1] += a.z * b.y; acc[2][2] += a.z * b.z; acc[2][3] += a.z * b.w;
                acc[3][0] += a.w * b.x; acc[3][1] += a.w * b.y; acc[3][2] += a.w * b.z; acc[3][3] += a.w * b.w;
            }
        }
    }

    // epilogue
    float bvals[4];
#pragma unroll
    for (int j = 0; j < 4; ++j) {
        const int gn = bn + n0 + j;
        bvals[j] = (gn < N) ? bias[gn] : 0.f;
    }
#pragma unroll
    for (int i = 0; i < 4; ++i) {
        const int gm = bm + m0 + i;
        if (gm >= M) continue;
        float* Crow = C + (size_t)gm * N;
#pragma unroll
        for (int j = 0; j < 4; ++j) {
            const int gn = bn + n0 + j;
            if (gn < N) {
                float v = acc[i][j] + bvals[j];
                if (RELU) v = fmaxf(v, 0.f);
                Crow[gn] = v;
            }
        }
    }
}

extern "C" void kernel_launch(void* const* d_in, const int* in_sizes, int n_in,
                              void* d_out, int out_size, void* d_ws, size_t ws_size,
                              hipStream_t stream) {
    (void)n_in; (void)out_size; (void)ws_size;

    const float* x    = (const float*)d_in[0];
    const int*   src0 = (const int*)d_in[1];
    const int*   dst0 = (const int*)d_in[2];
    const int*   src1 = (const int*)d_in[3];
    const int*   dst1 = (const int*)d_in[4];
    const int*   src2 = (const int*)d_in[5];
    const int*   dst2 = (const int*)d_in[6];
    const float* ws0  = (const float*)d_in[7];
    const float* wn0  = (const float*)d_in[8];
    const float* b0   = (const float*)d_in[9];
    const float* ws1  = (const float*)d_in[10];
    const float* wn1  = (const float*)d_in[11];
    const float* b1   = (const float*)d_in[12];
    const float* ws2  = (const float*)d_in[13];
    const float* wn2  = (const float*)d_in[14];
    const float* b2   = (const float*)d_in[15];

    const int E0 = in_sizes[1];
    const int E1 = in_sizes[3];
    const int E2 = in_sizes[5];
    const int N1 = 100000;   // n_dst0
    const int N2 = 25000;    // n_dst1
    const int N3 = 6250;     // n_dst2
    const int C  = 47;

    float* agg0 = (float*)d_ws;                       // [N1,256]
    float* agg1 = agg0 + (size_t)N1 * DIM;            // [N2,256]
    float* agg2 = agg1 + (size_t)N2 * DIM;            // [N3,256]
    float* h0   = agg2 + (size_t)N3 * DIM;            // [N1,256]
    float* h1   = h0   + (size_t)N1 * DIM;            // [N2,256]
    float* out  = (float*)d_out;                      // [N3,47]

    // zero the aggregation buffers (contiguous at front of workspace)
    const size_t agg_bytes = ((size_t)N1 + N2 + N3) * DIM * sizeof(float);
    hipMemsetAsync(d_ws, 0, agg_bytes, stream);

    // ---- layer 0 ----
    seg_sum_kernel<<<4096, 256, 0, stream>>>(x, src0, dst0, agg0, E0);
    {
        dim3 grid((N1 + 63) / 64, DIM / 64);
        sage_gemm_kernel<true><<<grid, 256, 0, stream>>>(x, agg0, ws0, wn0, b0, h0, N1, DIM);
    }
    // ---- layer 1 ----
    seg_sum_kernel<<<2048, 256, 0, stream>>>(h0, src1, dst1, agg1, E1);
    {
        dim3 grid((N2 + 63) / 64, DIM / 64);
        sage_gemm_kernel<true><<<grid, 256, 0, stream>>>(h0, agg1, ws1, wn1, b1, h1, N2, DIM);
    }
    // ---- layer 2 ----
    seg_sum_kernel<<<1024, 256, 0, stream>>>(h1, src2, dst2, agg2, E2);
    {
        dim3 grid((N3 + 63) / 64, (C + 63) / 64);
        sage_gemm_kernel<false><<<grid, 256, 0, stream>>>(h1, agg2, ws2, wn2, b2, out, N3, C);
    }
}

// Round 2
// 1485.818 us; speedup vs baseline: 5.3709x; 5.3709x over previous
//
#include <hip/hip_runtime.h>

// GraphSAGE 3-layer eval on MI355X.
// Layer l: agg = segment_sum(in[src], dst, n_dst); h = in[:n_dst]@Wself + agg@Wneigh + b; relu (l<2)
// Sizes: N0=400000, N1=100000, N2=25000, N3=6250, E0=1.6M, E1=400k, E2=100k, D=H=256, C=47.
//
// Aggregation strategy: bucket edges by dst (capacity 64, Poisson(16) tail => overflow P~1e-13),
// then one wave per dst gathers + register-accumulates src rows. No float atomics.

#define DIM 256
#define CAP 64

// ---------------- edge bucketing: one thread per edge ----------------
__global__ __launch_bounds__(256) void bucket_kernel(
    const int* __restrict__ src,
    const int* __restrict__ dst,
    int* __restrict__ cursor,       // [n_dst], pre-zeroed
    int* __restrict__ bucket,       // [n_dst * CAP]
    int E)
{
    int e = blockIdx.x * 256 + threadIdx.x;
    if (e >= E) return;
    const int d = dst[e];
    const int pos = atomicAdd(&cursor[d], 1);
    if (pos < CAP) bucket[(size_t)d * CAP + pos] = src[e];
}

// ---------------- gather aggregation: one wave per dst ----------------
__global__ __launch_bounds__(256) void agg_kernel(
    const float* __restrict__ X,       // [n_src, 256]
    const int* __restrict__ bucket,    // [n_dst * CAP]
    const int* __restrict__ cursor,    // [n_dst] = degree
    float* __restrict__ agg,           // [n_dst, 256]
    int n_dst)
{
    const int wave = (blockIdx.x << 2) + (threadIdx.x >> 6);
    if (wave >= n_dst) return;
    const int lane = threadIdx.x & 63;
    int deg = cursor[wave];
    if (deg > CAP) deg = CAP;
    const int* bk = bucket + (size_t)wave * CAP;

    float4 acc = make_float4(0.f, 0.f, 0.f, 0.f);
    int j = 0;
    for (; j + 2 <= deg; j += 2) {
        const int s0 = bk[j];
        const int s1 = bk[j + 1];
        const float4 v0 = *reinterpret_cast<const float4*>(X + (size_t)s0 * DIM + lane * 4);
        const float4 v1 = *reinterpret_cast<const float4*>(X + (size_t)s1 * DIM + lane * 4);
        acc.x += v0.x + v1.x;
        acc.y += v0.y + v1.y;
        acc.z += v0.z + v1.z;
        acc.w += v0.w + v1.w;
    }
    if (j < deg) {
        const int s0 = bk[j];
        const float4 v0 = *reinterpret_cast<const float4*>(X + (size_t)s0 * DIM + lane * 4);
        acc.x += v0.x;
        acc.y += v0.y;
        acc.z += v0.z;
        acc.w += v0.w;
    }
    *reinterpret_cast<float4*>(agg + (size_t)wave * DIM + lane * 4) = acc;
}

// ---------------- fused SAGE GEMM: C = A0@B0 + A1@B1 + bias (+relu) ----------------
// A0,A1: [M,256] row-major. B0,B1: [256,N] row-major. C: [M,N].
// 64x64 block tile, BK=16, 256 threads, 4x4 microtile per thread.
template<bool RELU>
__global__ __launch_bounds__(256) void sage_gemm_kernel(
    const float* __restrict__ A0,
    const float* __restrict__ A1,
    const float* __restrict__ B0,
    const float* __restrict__ B1,
    const float* __restrict__ bias,
    float* __restrict__ C,
    int M, int N)
{
    __shared__ float As[16][68];   // [k][m], pad 64->68
    __shared__ float Bs[16][64];   // [k][n]

    const int t  = threadIdx.x;
    const int bm = blockIdx.x * 64;
    const int bn = blockIdx.y * 64;

    const int a_row = t >> 2;           // 0..63
    const int a_k4  = (t & 3) << 2;     // 0,4,8,12
    const int b_k   = t >> 4;           // 0..15
    const int b_n4  = (t & 15) << 2;    // 0..60

    const int m0 = (t >> 4) << 2;
    const int n0 = (t & 15) << 2;

    float acc[4][4] = {};

    const int  gm_a      = bm + a_row;
    const bool a_ok      = (gm_a < M);
    const bool n_aligned = ((N & 3) == 0);

    for (int half = 0; half < 2; ++half) {
        const float* __restrict__ A = half ? A1 : A0;
        const float* __restrict__ B = half ? B1 : B0;
        for (int kb = 0; kb < DIM; kb += 16) {
            float4 av = make_float4(0.f, 0.f, 0.f, 0.f);
            if (a_ok)
                av = *reinterpret_cast<const float4*>(A + (size_t)gm_a * DIM + kb + a_k4);
            float4 bv;
            const int gk = kb + b_k;
            const int gn = bn + b_n4;
            if (n_aligned) {
                bv = *reinterpret_cast<const float4*>(B + (size_t)gk * N + gn);
            } else {
                const float* Brow = B + (size_t)gk * N;
                bv.x = (gn + 0 < N) ? Brow[gn + 0] : 0.f;
                bv.y = (gn + 1 < N) ? Brow[gn + 1] : 0.f;
                bv.z = (gn + 2 < N) ? Brow[gn + 2] : 0.f;
                bv.w = (gn + 3 < N) ? Brow[gn + 3] : 0.f;
            }

            __syncthreads();
            As[a_k4 + 0][a_row] = av.x;
            As[a_k4 + 1][a_row] = av.y;
            As[a_k4 + 2][a_row] = av.z;
            As[a_k4 + 3][a_row] = av.w;
            *reinterpret_cast<float4*>(&Bs[b_k][b_n4]) = bv;
            __syncthreads();

#pragma unroll
            for (int k = 0; k < 16; ++k) {
                const float4 a = *reinterpret_cast<const float4*>(&As[k][m0]);
                const float4 b = *reinterpret_cast<const float4*>(&Bs[k][n0]);
                acc[0][0] += a.x * b.x; acc[0][1] += a.x * b.y; acc[0][2] += a.x * b.z; acc[0][3] += a.x * b.w;
                acc[1][0] += a.y * b.x; acc[1][1] += a.y * b.y; acc[1][2] += a.y * b.z; acc[1][3] += a.y * b.w;
                acc[2][0] += a.z * b.x; acc[2][1] += a.z * b.y; acc[2][2] += a.z * b.z; acc[2][3] += a.z * b.w;
                acc[3][0] += a.w * b.x; acc[3][1] += a.w * b.y; acc[3][2] += a.w * b.z; acc[3][3] += a.w * b.w;
            }
        }
    }

    float bvals[4];
#pragma unroll
    for (int j = 0; j < 4; ++j) {
        const int gn = bn + n0 + j;
        bvals[j] = (gn < N) ? bias[gn] : 0.f;
    }
#pragma unroll
    for (int i = 0; i < 4; ++i) {
        const int gm = bm + m0 + i;
        if (gm >= M) continue;
        float* Crow = C + (size_t)gm * N;
#pragma unroll
        for (int j = 0; j < 4; ++j) {
            const int gn = bn + n0 + j;
            if (gn < N) {
                float v = acc[i][j] + bvals[j];
                if (RELU) v = fmaxf(v, 0.f);
                Crow[gn] = v;
            }
        }
    }
}

extern "C" void kernel_launch(void* const* d_in, const int* in_sizes, int n_in,
                              void* d_out, int out_size, void* d_ws, size_t ws_size,
                              hipStream_t stream) {
    (void)n_in; (void)out_size; (void)ws_size;

    const float* x    = (const float*)d_in[0];
    const int*   src0 = (const int*)d_in[1];
    const int*   dst0 = (const int*)d_in[2];
    const int*   src1 = (const int*)d_in[3];
    const int*   dst1 = (const int*)d_in[4];
    const int*   src2 = (const int*)d_in[5];
    const int*   dst2 = (const int*)d_in[6];
    const float* ws0  = (const float*)d_in[7];
    const float* wn0  = (const float*)d_in[8];
    const float* b0   = (const float*)d_in[9];
    const float* ws1  = (const float*)d_in[10];
    const float* wn1  = (const float*)d_in[11];
    const float* b1   = (const float*)d_in[12];
    const float* ws2  = (const float*)d_in[13];
    const float* wn2  = (const float*)d_in[14];
    const float* b2   = (const float*)d_in[15];

    const int E0 = in_sizes[1];
    const int E1 = in_sizes[3];
    const int E2 = in_sizes[5];
    const int N1 = 100000;   // n_dst0
    const int N2 = 25000;    // n_dst1
    const int N3 = 6250;     // n_dst2
    const int C  = 47;

    // workspace layout (all sizes multiples of 1 KB -> 16B alignment holds)
    float* agg    = (float*)d_ws;                     // [N1,256] (reused per layer)
    float* h0     = agg + (size_t)N1 * DIM;           // [N1,256]
    float* h1     = h0  + (size_t)N1 * DIM;           // [N2,256]
    int*   bucket = (int*)(h1 + (size_t)N2 * DIM);    // [N1*CAP]
    int*   cursor = bucket + (size_t)N1 * CAP;        // [N1]
    float* out    = (float*)d_out;                    // [N3,47]

    // ---- layer 0 ----
    hipMemsetAsync(cursor, 0, (size_t)N1 * sizeof(int), stream);
    bucket_kernel<<<(E0 + 255) / 256, 256, 0, stream>>>(src0, dst0, cursor, bucket, E0);
    agg_kernel<<<(N1 + 3) / 4, 256, 0, stream>>>(x, bucket, cursor, agg, N1);
    {
        dim3 grid((N1 + 63) / 64, DIM / 64);
        sage_gemm_kernel<true><<<grid, 256, 0, stream>>>(x, agg, ws0, wn0, b0, h0, N1, DIM);
    }
    // ---- layer 1 ----
    hipMemsetAsync(cursor, 0, (size_t)N2 * sizeof(int), stream);
    bucket_kernel<<<(E1 + 255) / 256, 256, 0, stream>>>(src1, dst1, cursor, bucket, E1);
    agg_kernel<<<(N2 + 3) / 4, 256, 0, stream>>>(h0, bucket, cursor, agg, N2);
    {
        dim3 grid((N2 + 63) / 64, DIM / 64);
        sage_gemm_kernel<true><<<grid, 256, 0, stream>>>(h0, agg, ws1, wn1, b1, h1, N2, DIM);
    }
    // ---- layer 2 ----
    hipMemsetAsync(cursor, 0, (size_t)N3 * sizeof(int), stream);
    bucket_kernel<<<(E2 + 255) / 256, 256, 0, stream>>>(src2, dst2, cursor, bucket, E2);
    agg_kernel<<<(N3 + 3) / 4, 256, 0, stream>>>(h1, bucket, cursor, agg, N3);
    {
        dim3 grid((N3 + 63) / 64, (C + 63) / 64);
        sage_gemm_kernel<false><<<grid, 256, 0, stream>>>(h1, agg, ws2, wn2, b2, out, N3, C);
    }
}

// Round 3
// 1048.906 us; speedup vs baseline: 7.6081x; 1.4165x over previous
//
#include <hip/hip_runtime.h>

// GraphSAGE 3-layer eval on MI355X (gfx950).
// Layer l: agg = segment_sum(in[src], dst, n_dst); h = in[:n_dst]@Wself + agg@Wneigh + b; relu (l<2)
// Sizes: N0=400000, N1=100000, N2=25000, N3=6250, E0=1.6M, E1=400k, E2=100k, D=H=256, C=47.
//
// R2: GEMMs -> bf16 MFMA (16x16x32), 128x128 tile, BK=32, global_load_lds staging.
//     Intermediates h0/h1/agg in bf16 (halves L1/L2 gather traffic). x stays f32
//     (L0 A-half staged with in-kernel f32->bf16 convert) to stay inside known-safe ws.

#define DIM 256
#define CAP 64

typedef __attribute__((ext_vector_type(8))) short bf16x8;
typedef __attribute__((ext_vector_type(4))) float f32x4;

__device__ __forceinline__ short f2bf(float f) {
    union { float f; unsigned u; } v; v.f = f;
    unsigned r = v.u + 0x7FFF + ((v.u >> 16) & 1);   // round-to-nearest-even
    return (short)(r >> 16);
}
__device__ __forceinline__ float bf2f(unsigned short h) {
    union { unsigned u; float f; } v; v.u = ((unsigned)h) << 16;
    return v.f;
}

#define GPTR(p) ((const __attribute__((address_space(1))) void*)(p))
#define LPTR(p) ((__attribute__((address_space(3))) void*)(p))

// ---------------- edge bucketing: one thread per edge ----------------
__global__ __launch_bounds__(256) void bucket_kernel(
    const int* __restrict__ src,
    const int* __restrict__ dst,
    int* __restrict__ cursor,       // [n_dst], pre-zeroed
    int* __restrict__ bucket,       // [n_dst * CAP]
    int E)
{
    int e = blockIdx.x * 256 + threadIdx.x;
    if (e >= E) return;
    const int d = dst[e];
    const int pos = atomicAdd(&cursor[d], 1);
    if (pos < CAP) bucket[(size_t)d * CAP + pos] = src[e];
}

// ---------------- gather aggregation: one wave per dst, bf16 output ----------------
template<bool F32IN>
__global__ __launch_bounds__(256) void agg_kernel(
    const void* __restrict__ Xv,       // [n_src, 256] f32 or bf16
    const int* __restrict__ bucket,    // [n_dst * CAP]
    const int* __restrict__ cursor,    // [n_dst] = degree
    short* __restrict__ agg,           // [n_dst, 256] bf16
    int n_dst)
{
    const int wave = (blockIdx.x << 2) + (threadIdx.x >> 6);
    if (wave >= n_dst) return;
    const int lane = threadIdx.x & 63;
    int deg = cursor[wave];
    if (deg > CAP) deg = CAP;
    const int* bk = bucket + (size_t)wave * CAP;

    float a0 = 0.f, a1 = 0.f, a2 = 0.f, a3 = 0.f;
    int j = 0;
    for (; j + 4 <= deg; j += 4) {
        const int s0 = bk[j], s1 = bk[j + 1], s2 = bk[j + 2], s3 = bk[j + 3];
        if (F32IN) {
            const float* X = (const float*)Xv;
            const float4 v0 = *(const float4*)(X + (size_t)s0 * DIM + lane * 4);
            const float4 v1 = *(const float4*)(X + (size_t)s1 * DIM + lane * 4);
            const float4 v2 = *(const float4*)(X + (size_t)s2 * DIM + lane * 4);
            const float4 v3 = *(const float4*)(X + (size_t)s3 * DIM + lane * 4);
            a0 += (v0.x + v1.x) + (v2.x + v3.x);
            a1 += (v0.y + v1.y) + (v2.y + v3.y);
            a2 += (v0.z + v1.z) + (v2.z + v3.z);
            a3 += (v0.w + v1.w) + (v2.w + v3.w);
        } else {
            const unsigned short* X = (const unsigned short*)Xv;
            const ushort4 u0 = *(const ushort4*)(X + (size_t)s0 * DIM + lane * 4);
            const ushort4 u1 = *(const ushort4*)(X + (size_t)s1 * DIM + lane * 4);
            const ushort4 u2 = *(const ushort4*)(X + (size_t)s2 * DIM + lane * 4);
            const ushort4 u3 = *(const ushort4*)(X + (size_t)s3 * DIM + lane * 4);
            a0 += (bf2f(u0.x) + bf2f(u1.x)) + (bf2f(u2.x) + bf2f(u3.x));
            a1 += (bf2f(u0.y) + bf2f(u1.y)) + (bf2f(u2.y) + bf2f(u3.y));
            a2 += (bf2f(u0.z) + bf2f(u1.z)) + (bf2f(u2.z) + bf2f(u3.z));
            a3 += (bf2f(u0.w) + bf2f(u1.w)) + (bf2f(u2.w) + bf2f(u3.w));
        }
    }
    for (; j < deg; ++j) {
        const int s0 = bk[j];
        if (F32IN) {
            const float* X = (const float*)Xv;
            const float4 v0 = *(const float4*)(X + (size_t)s0 * DIM + lane * 4);
            a0 += v0.x; a1 += v0.y; a2 += v0.z; a3 += v0.w;
        } else {
            const unsigned short* X = (const unsigned short*)Xv;
            const ushort4 u0 = *(const ushort4*)(X + (size_t)s0 * DIM + lane * 4);
            a0 += bf2f(u0.x); a1 += bf2f(u0.y); a2 += bf2f(u0.z); a3 += bf2f(u0.w);
        }
    }
    short4 o; o.x = f2bf(a0); o.y = f2bf(a1); o.z = f2bf(a2); o.w = f2bf(a3);
    *(short4*)(agg + (size_t)wave * DIM + lane * 4) = o;
}

// ---------------- weight transpose+convert: W[K,N] f32 -> Wt[NP,256] bf16 (zero-padded) ----------
__global__ __launch_bounds__(256) void wconv_kernel(
    const float* ws0, const float* wn0, const float* ws1, const float* wn1,
    const float* ws2, const float* wn2,
    short* t0, short* t1, short* t2, short* t3, short* t4, short* t5)
{
    const float* src; short* dst; int N, NP;
    switch (blockIdx.y) {
        case 0: src = ws0; dst = t0; N = 256; NP = 256; break;
        case 1: src = wn0; dst = t1; N = 256; NP = 256; break;
        case 2: src = ws1; dst = t2; N = 256; NP = 256; break;
        case 3: src = wn1; dst = t3; N = 256; NP = 256; break;
        case 4: src = ws2; dst = t4; N = 47;  NP = 128; break;
        default: src = wn2; dst = t5; N = 47; NP = 128; break;
    }
    int idx = blockIdx.x * 256 + threadIdx.x;
    if (idx >= NP * 256) return;
    int n = idx >> 8, k = idx & 255;
    float v = (n < N) ? src[(size_t)k * N + n] : 0.f;
    dst[(size_t)n * 256 + k] = f2bf(v);
}

// ---------------- MFMA GEMM: C = A0@B0^T + A1@B1^T + bias (+relu) ----------------
// A0: [M,256] f32 (A0F32) or bf16. A1: [M,256] bf16. B0,B1: [NP,256] bf16 (pre-transposed weights).
// C: [M,NV] f32 (OUTF32) or bf16 (NV=256). 128x128 tile, BK=32, 256 threads = 4 waves (2x2).
template<bool A0F32, bool RELU, bool OUTF32>
__global__ __launch_bounds__(256) void mfma_gemm(
    const void* __restrict__ A0v,
    const short* __restrict__ A1,
    const short* __restrict__ B0,
    const short* __restrict__ B1,
    const float* __restrict__ bias,
    void* __restrict__ Cv,
    int M, int NV)
{
    __shared__ short As[128 * 32];
    __shared__ short Bs[128 * 32];

    const int t  = threadIdx.x;
    const int bm = blockIdx.x * 128;
    const int bn = blockIdx.y * 128;

    // staging roles: thread t handles (row = t>>2 [+64], col8 = (t&3)*8)
    const int srow = t >> 2;
    const int scol = (t & 3) << 3;
    const int wv   = t >> 6;            // wave id 0..3

    // compute roles: wave (wm,wn) 2x2, each 64x64 = 4x4 mfma tiles
    const int wm = (wv & 1) << 6;
    const int wn = (wv >> 1) << 6;
    const int lr = t & 15;              // m (A) / n (B,D col)
    const int lq = (t & 63) >> 4;       // quad

    f32x4 acc[4][4];
#pragma unroll
    for (int i = 0; i < 4; ++i)
#pragma unroll
        for (int j = 0; j < 4; ++j) {
            acc[i][j][0] = 0.f; acc[i][j][1] = 0.f; acc[i][j][2] = 0.f; acc[i][j][3] = 0.f;
        }

    for (int half = 0; half < 2; ++half) {
        const short* Bh = half ? B1 : B0;
        for (int kb = 0; kb < 256; kb += 32) {
            // ---- stage A tile [128][32] bf16 ----
            if (A0F32 && half == 0) {
                const float* A = (const float*)A0v;
#pragma unroll
                for (int i = 0; i < 2; ++i) {
                    int row = srow + i * 64;
                    int gm = bm + row; if (gm >= M) gm = M - 1;
                    const float* g = A + (size_t)gm * 256 + kb + scol;
                    const float4 u = *(const float4*)g;
                    const float4 w = *(const float4*)(g + 4);
                    bf16x8 pk;
                    pk[0] = f2bf(u.x); pk[1] = f2bf(u.y); pk[2] = f2bf(u.z); pk[3] = f2bf(u.w);
                    pk[4] = f2bf(w.x); pk[5] = f2bf(w.y); pk[6] = f2bf(w.z); pk[7] = f2bf(w.w);
                    *(bf16x8*)(As + row * 32 + scol) = pk;
                }
            } else {
                const short* Ah = (half == 0) ? (const short*)A0v : A1;
#pragma unroll
                for (int i = 0; i < 2; ++i) {
                    int row = srow + i * 64;
                    int gm = bm + row; if (gm >= M) gm = M - 1;
                    const short* g = Ah + (size_t)gm * 256 + kb + scol;
                    __builtin_amdgcn_global_load_lds(GPTR(g), LPTR(As + i * 2048 + wv * 512), 16, 0, 0);
                }
            }
            // ---- stage B tile [128][32] bf16 ----
#pragma unroll
            for (int i = 0; i < 2; ++i) {
                int row = srow + i * 64;
                const short* g = Bh + (size_t)(bn + row) * 256 + kb + scol;
                __builtin_amdgcn_global_load_lds(GPTR(g), LPTR(Bs + i * 2048 + wv * 512), 16, 0, 0);
            }
            __syncthreads();

            // ---- fragments + MFMA ----
            bf16x8 af[4], bf[4];
#pragma unroll
            for (int i = 0; i < 4; ++i)
                af[i] = *(const bf16x8*)(As + (wm + i * 16 + lr) * 32 + lq * 8);
#pragma unroll
            for (int i = 0; i < 4; ++i)
                bf[i] = *(const bf16x8*)(Bs + (wn + i * 16 + lr) * 32 + lq * 8);
#pragma unroll
            for (int mt = 0; mt < 4; ++mt)
#pragma unroll
                for (int nt = 0; nt < 4; ++nt)
                    acc[mt][nt] = __builtin_amdgcn_mfma_f32_16x16x32_bf16(af[mt], bf[nt], acc[mt][nt], 0, 0, 0);
            __syncthreads();
        }
    }

    // ---- epilogue: D[row=lq*4+r][col=lr] per 16x16 tile ----
#pragma unroll
    for (int nt = 0; nt < 4; ++nt) {
        const int gn = bn + wn + nt * 16 + lr;
        const float bv = bias[gn < NV ? gn : 0];
#pragma unroll
        for (int mt = 0; mt < 4; ++mt) {
            const f32x4 a = acc[mt][nt];
#pragma unroll
            for (int r = 0; r < 4; ++r) {
                const int gm = bm + wm + mt * 16 + lq * 4 + r;
                if (gm < M && gn < NV) {
                    float v = a[r] + bv;
                    if (RELU) v = fmaxf(v, 0.f);
                    if (OUTF32) ((float*)Cv)[(size_t)gm * NV + gn] = v;
                    else        ((short*)Cv)[(size_t)gm * NV + gn] = f2bf(v);
                }
            }
        }
    }
}

extern "C" void kernel_launch(void* const* d_in, const int* in_sizes, int n_in,
                              void* d_out, int out_size, void* d_ws, size_t ws_size,
                              hipStream_t stream) {
    (void)n_in; (void)out_size; (void)ws_size;

    const float* x    = (const float*)d_in[0];
    const int*   src0 = (const int*)d_in[1];
    const int*   dst0 = (const int*)d_in[2];
    const int*   src1 = (const int*)d_in[3];
    const int*   dst1 = (const int*)d_in[4];
    const int*   src2 = (const int*)d_in[5];
    const int*   dst2 = (const int*)d_in[6];
    const float* ws0  = (const float*)d_in[7];
    const float* wn0  = (const float*)d_in[8];
    const float* b0   = (const float*)d_in[9];
    const float* ws1  = (const float*)d_in[10];
    const float* wn1  = (const float*)d_in[11];
    const float* b1   = (const float*)d_in[12];
    const float* ws2  = (const float*)d_in[13];
    const float* wn2  = (const float*)d_in[14];
    const float* b2   = (const float*)d_in[15];

    const int E0 = in_sizes[1];
    const int E1 = in_sizes[3];
    const int E2 = in_sizes[5];
    const int N1 = 100000, N2 = 25000, N3 = 6250;

    // workspace layout (256B aligned chunks), total ~142 MB
    char* p = (char*)d_ws;
    auto alloc = [&](size_t bytes) { char* r = p; p += (bytes + 255) & ~(size_t)255; return r; };
    short* h0     = (short*)alloc((size_t)N1 * DIM * 2);
    short* h1     = (short*)alloc((size_t)N2 * DIM * 2);
    short* agg    = (short*)alloc((size_t)N1 * DIM * 2);
    int*   bucket = (int*)alloc((size_t)N1 * CAP * 4);
    int*   curs   = (int*)alloc((size_t)(N1 + N2 + N3) * 4);
    short* wt0s   = (short*)alloc(256 * 256 * 2);
    short* wt0n   = (short*)alloc(256 * 256 * 2);
    short* wt1s   = (short*)alloc(256 * 256 * 2);
    short* wt1n   = (short*)alloc(256 * 256 * 2);
    short* wt2s   = (short*)alloc(128 * 256 * 2);
    short* wt2n   = (short*)alloc(128 * 256 * 2);
    int* cur0 = curs, *cur1 = curs + N1, *cur2 = curs + N1 + N2;

    wconv_kernel<<<dim3(256, 6), 256, 0, stream>>>(ws0, wn0, ws1, wn1, ws2, wn2,
                                                   wt0s, wt0n, wt1s, wt1n, wt2s, wt2n);
    hipMemsetAsync(curs, 0, (size_t)(N1 + N2 + N3) * 4, stream);

    // ---- layer 0 ----
    bucket_kernel<<<(E0 + 255) / 256, 256, 0, stream>>>(src0, dst0, cur0, bucket, E0);
    agg_kernel<true><<<(N1 + 3) / 4, 256, 0, stream>>>(x, bucket, cur0, agg, N1);
    mfma_gemm<true, true, false><<<dim3((N1 + 127) / 128, 2), 256, 0, stream>>>(
        x, agg, wt0s, wt0n, b0, h0, N1, 256);
    // ---- layer 1 ----
    bucket_kernel<<<(E1 + 255) / 256, 256, 0, stream>>>(src1, dst1, cur1, bucket, E1);
    agg_kernel<false><<<(N2 + 3) / 4, 256, 0, stream>>>(h0, bucket, cur1, agg, N2);
    mfma_gemm<false, true, false><<<dim3((N2 + 127) / 128, 2), 256, 0, stream>>>(
        h0, agg, wt1s, wt1n, b1, h1, N2, 256);
    // ---- layer 2 ----
    bucket_kernel<<<(E2 + 255) / 256, 256, 0, stream>>>(src2, dst2, cur2, bucket, E2);
    agg_kernel<false><<<(N3 + 3) / 4, 256, 0, stream>>>(h1, bucket, cur2, agg, N3);
    mfma_gemm<false, false, true><<<dim3((N3 + 127) / 128, 1), 256, 0, stream>>>(
        h1, agg, wt2s, wt2n, b2, d_out, N3, 47);
}

// Round 4
// 1040.784 us; speedup vs baseline: 7.6674x; 1.0078x over previous
//
#include <hip/hip_runtime.h>

// GraphSAGE 3-layer eval on MI355X (gfx950).
// Layer l: agg = segment_sum(in[src], dst, n_dst); h = in[:n_dst]@Wself + agg@Wneigh + b; relu (l<2)
// Sizes: N0=400000, N1=100000, N2=25000, N3=6250, E0=1.6M, E1=400k, E2=100k, D=H=256, C=47.
//
// R3: pre-convert x->bf16 (halves gather bytes; 205MB ~ fits L3) guarded by ws_size check;
//     pure-bf16 MFMA GEMM everywhere (all staging via global_load_lds); merged bucket kernel.

#define DIM 256
#define CAP 64

typedef __attribute__((ext_vector_type(8))) short bf16x8;
typedef __attribute__((ext_vector_type(4))) float f32x4;

__device__ __forceinline__ short f2bf(float f) {
    union { float f; unsigned u; } v; v.f = f;
    unsigned r = v.u + 0x7FFF + ((v.u >> 16) & 1);   // round-to-nearest-even
    return (short)(r >> 16);
}
__device__ __forceinline__ float bf2f(unsigned short h) {
    union { unsigned u; float f; } v; v.u = ((unsigned)h) << 16;
    return v.f;
}

#define GPTR(p) ((const __attribute__((address_space(1))) void*)(p))
#define LPTR(p) ((__attribute__((address_space(3))) void*)(p))

// ---------------- x f32 -> bf16 streaming convert ----------------
__global__ __launch_bounds__(256) void conv_x_kernel(
    const float* __restrict__ x, short* __restrict__ xb, int n4)
{
    int i = blockIdx.x * 256 + threadIdx.x;
    const int stride = gridDim.x * 256;
    for (; i < n4; i += stride) {
        const float4 v = ((const float4*)x)[i];
        short4 o;
        o.x = f2bf(v.x); o.y = f2bf(v.y); o.z = f2bf(v.z); o.w = f2bf(v.w);
        ((short4*)xb)[i] = o;
    }
}

// ---------------- edge bucketing, all 3 layers in one launch ----------------
__global__ __launch_bounds__(256) void bucket_all_kernel(
    const int* __restrict__ src0, const int* __restrict__ dst0, int E0,
    const int* __restrict__ src1, const int* __restrict__ dst1, int E1,
    const int* __restrict__ src2, const int* __restrict__ dst2, int E2,
    int* __restrict__ cur0, int* __restrict__ cur1, int* __restrict__ cur2,
    int* __restrict__ bk0, int* __restrict__ bk1, int* __restrict__ bk2)
{
    int e = blockIdx.x * 256 + threadIdx.x;
    const int* s; const int* d; int* cur; int* bk;
    if (e < E0)           { s = src0; d = dst0; cur = cur0; bk = bk0; }
    else if (e < E0 + E1) { e -= E0; s = src1; d = dst1; cur = cur1; bk = bk1; }
    else if (e < E0 + E1 + E2) { e -= E0 + E1; s = src2; d = dst2; cur = cur2; bk = bk2; }
    else return;
    const int dd = d[e];
    const int pos = atomicAdd(&cur[dd], 1);
    if (pos < CAP) bk[(size_t)dd * CAP + pos] = s[e];
}

// ---------------- gather aggregation: one wave per dst, bf16 output ----------------
template<bool F32IN>
__global__ __launch_bounds__(256) void agg_kernel(
    const void* __restrict__ Xv,       // [n_src, 256] f32 or bf16
    const int* __restrict__ bucket,    // [n_dst * CAP]
    const int* __restrict__ cursor,    // [n_dst] = degree
    short* __restrict__ agg,           // [n_dst, 256] bf16
    int n_dst)
{
    const int wave = (blockIdx.x << 2) + (threadIdx.x >> 6);
    if (wave >= n_dst) return;
    const int lane = threadIdx.x & 63;
    int deg = cursor[wave];
    if (deg > CAP) deg = CAP;
    const int* bk = bucket + (size_t)wave * CAP;

    float a0 = 0.f, a1 = 0.f, a2 = 0.f, a3 = 0.f;
    int j = 0;
    for (; j + 4 <= deg; j += 4) {
        const int s0 = bk[j], s1 = bk[j + 1], s2 = bk[j + 2], s3 = bk[j + 3];
        if (F32IN) {
            const float* X = (const float*)Xv;
            const float4 v0 = *(const float4*)(X + (size_t)s0 * DIM + lane * 4);
            const float4 v1 = *(const float4*)(X + (size_t)s1 * DIM + lane * 4);
            const float4 v2 = *(const float4*)(X + (size_t)s2 * DIM + lane * 4);
            const float4 v3 = *(const float4*)(X + (size_t)s3 * DIM + lane * 4);
            a0 += (v0.x + v1.x) + (v2.x + v3.x);
            a1 += (v0.y + v1.y) + (v2.y + v3.y);
            a2 += (v0.z + v1.z) + (v2.z + v3.z);
            a3 += (v0.w + v1.w) + (v2.w + v3.w);
        } else {
            const unsigned short* X = (const unsigned short*)Xv;
            const ushort4 u0 = *(const ushort4*)(X + (size_t)s0 * DIM + lane * 4);
            const ushort4 u1 = *(const ushort4*)(X + (size_t)s1 * DIM + lane * 4);
            const ushort4 u2 = *(const ushort4*)(X + (size_t)s2 * DIM + lane * 4);
            const ushort4 u3 = *(const ushort4*)(X + (size_t)s3 * DIM + lane * 4);
            a0 += (bf2f(u0.x) + bf2f(u1.x)) + (bf2f(u2.x) + bf2f(u3.x));
            a1 += (bf2f(u0.y) + bf2f(u1.y)) + (bf2f(u2.y) + bf2f(u3.y));
            a2 += (bf2f(u0.z) + bf2f(u1.z)) + (bf2f(u2.z) + bf2f(u3.z));
            a3 += (bf2f(u0.w) + bf2f(u1.w)) + (bf2f(u2.w) + bf2f(u3.w));
        }
    }
    for (; j < deg; ++j) {
        const int s0 = bk[j];
        if (F32IN) {
            const float* X = (const float*)Xv;
            const float4 v0 = *(const float4*)(X + (size_t)s0 * DIM + lane * 4);
            a0 += v0.x; a1 += v0.y; a2 += v0.z; a3 += v0.w;
        } else {
            const unsigned short* X = (const unsigned short*)Xv;
            const ushort4 u0 = *(const ushort4*)(X + (size_t)s0 * DIM + lane * 4);
            a0 += bf2f(u0.x); a1 += bf2f(u0.y); a2 += bf2f(u0.z); a3 += bf2f(u0.w);
        }
    }
    short4 o; o.x = f2bf(a0); o.y = f2bf(a1); o.z = f2bf(a2); o.w = f2bf(a3);
    *(short4*)(agg + (size_t)wave * DIM + lane * 4) = o;
}

// ---------------- weight transpose+convert: W[K,N] f32 -> Wt[NP,256] bf16 (zero-padded) ----------
__global__ __launch_bounds__(256) void wconv_kernel(
    const float* ws0, const float* wn0, const float* ws1, const float* wn1,
    const float* ws2, const float* wn2,
    short* t0, short* t1, short* t2, short* t3, short* t4, short* t5)
{
    const float* src; short* dst; int N, NP;
    switch (blockIdx.y) {
        case 0: src = ws0; dst = t0; N = 256; NP = 256; break;
        case 1: src = wn0; dst = t1; N = 256; NP = 256; break;
        case 2: src = ws1; dst = t2; N = 256; NP = 256; break;
        case 3: src = wn1; dst = t3; N = 256; NP = 256; break;
        case 4: src = ws2; dst = t4; N = 47;  NP = 128; break;
        default: src = wn2; dst = t5; N = 47; NP = 128; break;
    }
    int idx = blockIdx.x * 256 + threadIdx.x;
    if (idx >= NP * 256) return;
    int n = idx >> 8, k = idx & 255;
    float v = (n < N) ? src[(size_t)k * N + n] : 0.f;
    dst[(size_t)n * 256 + k] = f2bf(v);
}

// ---------------- MFMA GEMM: C = A0@B0^T + A1@B1^T + bias (+relu) ----------------
// A0: [M,256] f32 (A0F32) or bf16. A1: [M,256] bf16. B0,B1: [NP,256] bf16 (pre-transposed weights).
// C: [M,NV] f32 (OUTF32) or bf16 (NV=256). 128x128 tile, BK=32, 256 threads = 4 waves (2x2).
template<bool A0F32, bool RELU, bool OUTF32>
__global__ __launch_bounds__(256) void mfma_gemm(
    const void* __restrict__ A0v,
    const short* __restrict__ A1,
    const short* __restrict__ B0,
    const short* __restrict__ B1,
    const float* __restrict__ bias,
    void* __restrict__ Cv,
    int M, int NV)
{
    __shared__ short As[128 * 32];
    __shared__ short Bs[128 * 32];

    const int t  = threadIdx.x;
    const int bm = blockIdx.x * 128;
    const int bn = blockIdx.y * 128;

    const int srow = t >> 2;
    const int scol = (t & 3) << 3;
    const int wv   = t >> 6;

    const int wm = (wv & 1) << 6;
    const int wn = (wv >> 1) << 6;
    const int lr = t & 15;
    const int lq = (t & 63) >> 4;

    f32x4 acc[4][4];
#pragma unroll
    for (int i = 0; i < 4; ++i)
#pragma unroll
        for (int j = 0; j < 4; ++j) {
            acc[i][j][0] = 0.f; acc[i][j][1] = 0.f; acc[i][j][2] = 0.f; acc[i][j][3] = 0.f;
        }

    for (int half = 0; half < 2; ++half) {
        const short* Bh = half ? B1 : B0;
        for (int kb = 0; kb < 256; kb += 32) {
            if (A0F32 && half == 0) {
                const float* A = (const float*)A0v;
#pragma unroll
                for (int i = 0; i < 2; ++i) {
                    int row = srow + i * 64;
                    int gm = bm + row; if (gm >= M) gm = M - 1;
                    const float* g = A + (size_t)gm * 256 + kb + scol;
                    const float4 u = *(const float4*)g;
                    const float4 w = *(const float4*)(g + 4);
                    bf16x8 pk;
                    pk[0] = f2bf(u.x); pk[1] = f2bf(u.y); pk[2] = f2bf(u.z); pk[3] = f2bf(u.w);
                    pk[4] = f2bf(w.x); pk[5] = f2bf(w.y); pk[6] = f2bf(w.z); pk[7] = f2bf(w.w);
                    *(bf16x8*)(As + row * 32 + scol) = pk;
                }
            } else {
                const short* Ah = (half == 0) ? (const short*)A0v : A1;
#pragma unroll
                for (int i = 0; i < 2; ++i) {
                    int row = srow + i * 64;
                    int gm = bm + row; if (gm >= M) gm = M - 1;
                    const short* g = Ah + (size_t)gm * 256 + kb + scol;
                    __builtin_amdgcn_global_load_lds(GPTR(g), LPTR(As + i * 2048 + wv * 512), 16, 0, 0);
                }
            }
#pragma unroll
            for (int i = 0; i < 2; ++i) {
                int row = srow + i * 64;
                const short* g = Bh + (size_t)(bn + row) * 256 + kb + scol;
                __builtin_amdgcn_global_load_lds(GPTR(g), LPTR(Bs + i * 2048 + wv * 512), 16, 0, 0);
            }
            __syncthreads();

            bf16x8 af[4], bfr[4];
#pragma unroll
            for (int i = 0; i < 4; ++i)
                af[i] = *(const bf16x8*)(As + (wm + i * 16 + lr) * 32 + lq * 8);
#pragma unroll
            for (int i = 0; i < 4; ++i)
                bfr[i] = *(const bf16x8*)(Bs + (wn + i * 16 + lr) * 32 + lq * 8);
#pragma unroll
            for (int mt = 0; mt < 4; ++mt)
#pragma unroll
                for (int nt = 0; nt < 4; ++nt)
                    acc[mt][nt] = __builtin_amdgcn_mfma_f32_16x16x32_bf16(af[mt], bfr[nt], acc[mt][nt], 0, 0, 0);
            __syncthreads();
        }
    }

#pragma unroll
    for (int nt = 0; nt < 4; ++nt) {
        const int gn = bn + wn + nt * 16 + lr;
        const float bv = bias[gn < NV ? gn : 0];
#pragma unroll
        for (int mt = 0; mt < 4; ++mt) {
            const f32x4 a = acc[mt][nt];
#pragma unroll
            for (int r = 0; r < 4; ++r) {
                const int gm = bm + wm + mt * 16 + lq * 4 + r;
                if (gm < M && gn < NV) {
                    float v = a[r] + bv;
                    if (RELU) v = fmaxf(v, 0.f);
                    if (OUTF32) ((float*)Cv)[(size_t)gm * NV + gn] = v;
                    else        ((short*)Cv)[(size_t)gm * NV + gn] = f2bf(v);
                }
            }
        }
    }
}

extern "C" void kernel_launch(void* const* d_in, const int* in_sizes, int n_in,
                              void* d_out, int out_size, void* d_ws, size_t ws_size,
                              hipStream_t stream) {
    (void)n_in; (void)out_size;

    const float* x    = (const float*)d_in[0];
    const int*   src0 = (const int*)d_in[1];
    const int*   dst0 = (const int*)d_in[2];
    const int*   src1 = (const int*)d_in[3];
    const int*   dst1 = (const int*)d_in[4];
    const int*   src2 = (const int*)d_in[5];
    const int*   dst2 = (const int*)d_in[6];
    const float* ws0  = (const float*)d_in[7];
    const float* wn0  = (const float*)d_in[8];
    const float* b0   = (const float*)d_in[9];
    const float* ws1  = (const float*)d_in[10];
    const float* wn1  = (const float*)d_in[11];
    const float* b1   = (const float*)d_in[12];
    const float* ws2  = (const float*)d_in[13];
    const float* wn2  = (const float*)d_in[14];
    const float* b2   = (const float*)d_in[15];

    const int E0 = in_sizes[1];
    const int E1 = in_sizes[3];
    const int E2 = in_sizes[5];
    const int N0 = 400000, N1 = 100000, N2 = 25000, N3 = 6250;

    char* p = (char*)d_ws;
    auto alloc = [&](size_t bytes) { char* r = p; p += (bytes + 255) & ~(size_t)255; return r; };
    short* h0   = (short*)alloc((size_t)N1 * DIM * 2);
    short* h1   = (short*)alloc((size_t)N2 * DIM * 2);
    short* agg  = (short*)alloc((size_t)N1 * DIM * 2);
    int*   bk0  = (int*)alloc((size_t)N1 * CAP * 4);
    int*   bk1  = (int*)alloc((size_t)N2 * CAP * 4);
    int*   bk2  = (int*)alloc((size_t)N3 * CAP * 4);
    int*   curs = (int*)alloc((size_t)(N1 + N2 + N3) * 4);
    short* wt0s = (short*)alloc(256 * 256 * 2);
    short* wt0n = (short*)alloc(256 * 256 * 2);
    short* wt1s = (short*)alloc(256 * 256 * 2);
    short* wt1n = (short*)alloc(256 * 256 * 2);
    short* wt2s = (short*)alloc(128 * 256 * 2);
    short* wt2n = (short*)alloc(128 * 256 * 2);
    const size_t base_bytes = (size_t)(p - (char*)d_ws);
    const size_t xbf_bytes  = (size_t)N0 * DIM * 2;
    const bool   use_xbf    = (base_bytes + xbf_bytes) <= ws_size;
    short* x_bf = (short*)alloc(xbf_bytes);          // only used if use_xbf

    int* cur0 = curs, *cur1 = curs + N1, *cur2 = curs + N1 + N2;
    const int Etot = E0 + E1 + E2;

    if (use_xbf)
        conv_x_kernel<<<8192, 256, 0, stream>>>(x, x_bf, N0 * DIM / 4);
    wconv_kernel<<<dim3(256, 6), 256, 0, stream>>>(ws0, wn0, ws1, wn1, ws2, wn2,
                                                   wt0s, wt0n, wt1s, wt1n, wt2s, wt2n);
    hipMemsetAsync(curs, 0, (size_t)(N1 + N2 + N3) * 4, stream);
    bucket_all_kernel<<<(Etot + 255) / 256, 256, 0, stream>>>(
        src0, dst0, E0, src1, dst1, E1, src2, dst2, E2,
        cur0, cur1, cur2, bk0, bk1, bk2);

    // ---- layer 0 ----
    if (use_xbf) {
        agg_kernel<false><<<(N1 + 3) / 4, 256, 0, stream>>>(x_bf, bk0, cur0, agg, N1);
        mfma_gemm<false, true, false><<<dim3((N1 + 127) / 128, 2), 256, 0, stream>>>(
            x_bf, agg, wt0s, wt0n, b0, h0, N1, 256);
    } else {
        agg_kernel<true><<<(N1 + 3) / 4, 256, 0, stream>>>(x, bk0, cur0, agg, N1);
        mfma_gemm<true, true, false><<<dim3((N1 + 127) / 128, 2), 256, 0, stream>>>(
            x, agg, wt0s, wt0n, b0, h0, N1, 256);
    }
    // ---- layer 1 ----
    agg_kernel<false><<<(N2 + 3) / 4, 256, 0, stream>>>(h0, bk1, cur1, agg, N2);
    mfma_gemm<false, true, false><<<dim3((N2 + 127) / 128, 2), 256, 0, stream>>>(
        h0, agg, wt1s, wt1n, b1, h1, N2, 256);
    // ---- layer 2 ----
    agg_kernel<false><<<(N3 + 3) / 4, 256, 0, stream>>>(h1, bk2, cur2, agg, N3);
    mfma_gemm<false, false, true><<<dim3((N3 + 127) / 128, 1), 256, 0, stream>>>(
        h1, agg, wt2s, wt2n, b2, d_out, N3, 47);
}